// Round 2
// baseline (123.543 us; speedup 1.0000x reference)
//
#include <hip/hip_runtime.h>

#define BIG 1e10f
#define H 256
#define W 256
#define NPIX (H * W)
// images: 0..7 = pred batch, 8..15 = target batch
// ws layout:
//   [0, 16384)            double partial[2048]   (one per row_pass block)
//   [16384, 16448)        int flags[16]          (fg.any() per image)
//   [32768, 32768+8MB)    float2 g2[16][H][W]    ({fg_g^2, bg_g^2} per pixel)

// ---------------------------------------------------------------------------
// Kernel 1: column pass. One thread per (image, column); 64 blocks x 64 thr
// so 64 CUs share the latency of the two serial 256-step scans. Computes the
// vertical 1-D distance for BOTH masks, clamped at BIG, squared, stored as
// one coalesced float2 {fg^2, bg^2}. Inclusive cummax semantics match the
// reference exactly (g==0 at a mask's own background pixels automatically).
// ---------------------------------------------------------------------------
__global__ __launch_bounds__(64) void col_pass(
    const float* __restrict__ pred, const float* __restrict__ targ,
    float2* __restrict__ g2, int* __restrict__ flags) {
  const int img = blockIdx.x >> 2;                       // 0..15
  const int col = ((blockIdx.x & 3) << 6) + threadIdx.x; // 0..255
  const float* __restrict__ src =
      (img < 8) ? pred + img * NPIX : targ + (img - 8) * NPIX;
  float2* __restrict__ g = g2 + img * NPIX;

  // downward: distance to nearest mask-background above (inclusive)
  float lastF = -BIG;  // fg-mask background = !fg pixel
  float lastB = -BIG;  // bg-mask background = fg pixel
  int any = 0;
#pragma unroll 4
  for (int i = 0; i < H; ++i) {
    const float v = src[i * W + col];
    const float fi = (float)i;
    if (v > 0.5f) { lastB = fi; any = 1; } else { lastF = fi; }
    g[i * W + col] = make_float2(fi - lastF, fi - lastB);
  }
  if (any) atomicOr(&flags[img], 1);

  // upward: min with distance below, clamp at BIG, square
  float nextF = BIG, nextB = BIG;
#pragma unroll 4
  for (int i = H - 1; i >= 0; --i) {
    const float v = src[i * W + col];
    const float fi = (float)i;
    if (v > 0.5f) { nextB = fi; } else { nextF = fi; }
    const float2 d = g[i * W + col];
    const float dF = fminf(fminf(d.x, nextF - fi), BIG);
    const float dB = fminf(fminf(d.y, nextB - fi), BIG);
    g[i * W + col] = make_float2(dF * dF, dB * dB);
  }
}

// ---------------------------------------------------------------------------
// Kernel 2: row pass + loss. One block per (batch, row). Disjoint-support
// selection: a pixel's field^2 equals the EDT^2 of whichever mask it belongs
// to, so each thread scans ONE envelope per image (base pointer selected
// before the loop by its own pixel's mask — loop-invariant, no divergence).
// LDS reads are 2 distinct addresses per wave -> broadcast, conflict-free.
// ---------------------------------------------------------------------------
__global__ __launch_bounds__(256) void row_pass(
    const float* __restrict__ pred, const float* __restrict__ targ,
    const float2* __restrict__ g2, const int* __restrict__ flags,
    double* __restrict__ partial) {
  const int b = blockIdx.x >> 8;       // batch 0..7
  const int i = blockIdx.x & (H - 1);  // row
  const int j = threadIdx.x;           // column

  __shared__ float2 gsP[W], gsT[W];    // {fg^2, bg^2} rows for pred / target
  gsP[j] = g2[b * NPIX + i * W + j];
  gsT[j] = g2[(8 + b) * NPIX + i * W + j];
  const int pix = b * NPIX + i * W + j;
  const float p = pred[pix];
  const float t = targ[pix];
  __syncthreads();

  // fg pixel -> edt(fg)^2 (offset 0); bg pixel -> edt(bg)^2 (offset 1)
  const float* __restrict__ baseP = ((const float*)gsP) + (p > 0.5f ? 0 : 1);
  const float* __restrict__ baseT = ((const float*)gsT) + (t > 0.5f ? 0 : 1);

  float dP = 3.0e38f, dT = 3.0e38f;
  float diff = (float)j;  // j - k, decremented each iteration
#pragma unroll 8
  for (int k = 0; k < W; ++k) {
    const float q = diff * diff;
    dP = fminf(dP, q + baseP[2 * k]);
    dT = fminf(dT, q + baseT[2 * k]);
    diff -= 1.0f;
  }

  const float fP = flags[b] ? 1.0f : 0.0f;      // zero field if no fg (ref)
  const float fT = flags[8 + b] ? 1.0f : 0.0f;
  const float pe = (p - t) * (p - t);
  double c = (double)(pe * (dP * fP + dT * fT));

  // wave reduce then cross-wave via LDS; plain store (no atomics)
  for (int off = 32; off > 0; off >>= 1) c += __shfl_down(c, off);
  __shared__ double wsum[4];
  if ((j & 63) == 0) wsum[j >> 6] = c;
  __syncthreads();
  if (j == 0) partial[blockIdx.x] = wsum[0] + wsum[1] + wsum[2] + wsum[3];
}

// ---------------------------------------------------------------------------
// Kernel 3: reduce 2048 partials, scale, write fp32 result.
// ---------------------------------------------------------------------------
__global__ __launch_bounds__(256) void finalize(
    const double* __restrict__ partial, float* __restrict__ out) {
  double s = 0.0;
#pragma unroll
  for (int k = 0; k < 8; ++k) s += partial[threadIdx.x + (k << 8)];
  for (int off = 32; off > 0; off >>= 1) s += __shfl_down(s, off);
  __shared__ double ws[4];
  if ((threadIdx.x & 63) == 0) ws[threadIdx.x >> 6] = s;
  __syncthreads();
  if (threadIdx.x == 0)
    out[0] = (float)((ws[0] + ws[1] + ws[2] + ws[3]) *
                     (1.0 / (8.0 * (double)NPIX)));
}

extern "C" void kernel_launch(void* const* d_in, const int* in_sizes, int n_in,
                              void* d_out, int out_size, void* d_ws,
                              size_t ws_size, hipStream_t stream) {
  const float* pred = (const float*)d_in[0];
  const float* targ = (const float*)d_in[1];
  double* partial = (double*)d_ws;
  int* flags = (int*)((char*)d_ws + 16384);
  float2* g2 = (float2*)((char*)d_ws + 32768);

  hipMemsetAsync(flags, 0, 64, stream);  // zero fg.any() flags only
  col_pass<<<64, 64, 0, stream>>>(pred, targ, g2, flags);
  row_pass<<<8 * H, 256, 0, stream>>>(pred, targ, g2, flags, partial);
  finalize<<<1, 256, 0, stream>>>(partial, (float*)d_out);
}